// Round 10
// baseline (32.333 us; speedup 1.0000x reference)
//
#include <hip/hip_runtime.h>
#include <math.h>

typedef _Float16 f16;
typedef f16 f16x8 __attribute__((ext_vector_type(8)));
typedef float f32x16 __attribute__((ext_vector_type(16)));

static constexpr int Bn = 16;
static constexpr int Kn = 4096;
static constexpr int NPTS = Bn * Kn;    // 65536
static constexpr int MGRID = 512;       // qg8(16) x b(16) x dir(2)
static constexpr int NPSUM = 1024;      // psum keeps the OLD 1024-slot layout
static constexpr float WBIG = 49152.0f; // exact in fp16
static constexpr float QMIN0 = 3e37f;

static constexpr size_t FRAG_BYTES = (size_t)NPTS * 32;

// 16 K-slot values (13 used) for v_mfma_f32_32x32x16_f16:
// d2[r][q] = sum_k A[r][k]*B[k][q]
//  k0..8 : error-compensated -2*dot (hh, hl, lh per coord)
//  k9,10 : ref ||.||^2 (hi,lo) * 1 ;  k11,12: 1 * query ||.||^2 (hi,lo)
// invalid as ref: w=+WBIG (never wins min); invalid as query: w=-WBIG
// (min << -1e4 -> dropped at the sqrt stage).
__device__ inline void mk_slots(float x, float y, float z, bool valid,
                                f16 A[16], f16 B[16]) {
    float w = fmaf(x, x, fmaf(y, y, z * z));
    f16 xh = (f16)x, yh = (f16)y, zh = (f16)z;
    f16 xl = (f16)(x - (float)xh), yl = (f16)(y - (float)yh), zl = (f16)(z - (float)zh);
    f16 m2xh = (f16)(-2.0f * (float)xh), m2xl = (f16)(-2.0f * (float)xl);
    f16 m2yh = (f16)(-2.0f * (float)yh), m2yl = (f16)(-2.0f * (float)yl);
    f16 m2zh = (f16)(-2.0f * (float)zh), m2zl = (f16)(-2.0f * (float)zl);
    f16 one = (f16)1.0f, zero = (f16)0.0f;
    f16 whA, wlA, whB, wlB;
    if (valid) {
        f16 wh = (f16)w; f16 wl = (f16)(w - (float)wh);
        whA = wh; wlA = wl; whB = wh; wlB = wl;
    } else {
        whA = (f16)WBIG;   wlA = zero;
        whB = (f16)(-WBIG); wlB = zero;
    }
    A[0] = m2xh; A[1] = m2xh; A[2] = m2xl;
    A[3] = m2yh; A[4] = m2yh; A[5] = m2yl;
    A[6] = m2zh; A[7] = m2zh; A[8] = m2zl;
    A[9] = whA; A[10] = wlA; A[11] = one; A[12] = one;
    A[13] = zero; A[14] = zero; A[15] = zero;
    B[0] = xh; B[1] = xl; B[2] = xh;
    B[3] = yh; B[4] = yl; B[5] = yh;
    B[6] = zh; B[7] = zl; B[8] = zh;
    B[9] = one; B[10] = one; B[11] = whB; B[12] = wlB;
    B[13] = zero; B[14] = zero; B[15] = zero;
}

// 32x32x16 tile = 64 entries of f16x8. Lane l -> row/col = l&31, k-group
// g = l>>5. Entry index: g*32 + r. A-slot j and B-slot j at the same (g, i)
// position -> products pair under any shared k-bijection.
// Also writes the opaque 64-B zero block for the mfma kernel's C operand,
// and re-zeroes the completion ticket (graph replay order: prep -> mfma).
__global__ __launch_bounds__(256) void prep_kernel(
        const float* __restrict__ pred, const float* __restrict__ target,
        const int* __restrict__ mask,
        f16x8* __restrict__ predA, f16x8* __restrict__ predB,
        f16x8* __restrict__ tgtA, f16x8* __restrict__ tgtB,
        unsigned int* __restrict__ cnt4, float* __restrict__ czero,
        unsigned int* __restrict__ ticket) {
    int idx = blockIdx.x * 256 + threadIdx.x;
    if (idx < 16) czero[idx] = 0.0f;
    if (idx == 16) *ticket = 0u;
    bool valid = mask[idx] != 0;

    float px = pred[idx * 3 + 0], py = pred[idx * 3 + 1], pz = pred[idx * 3 + 2];
    float tx = target[idx * 3 + 0], ty = target[idx * 3 + 1], tz = target[idx * 3 + 2];
    if (!valid) { px = py = pz = 0.0f; tx = ty = tz = 0.0f; }

    f16 PA[16], PB[16], TA[16], TB[16];
    mk_slots(px, py, pz, valid, PA, PB);
    mk_slots(tx, ty, tz, valid, TA, TB);

    int b = idx >> 12, kk = idx & 4095;
    int rt = kk >> 5, r = kk & 31;
    size_t base = ((size_t)(b * 128 + rt)) * 64;

    #pragma unroll
    for (int g = 0; g < 2; ++g) {
        int o = g * 8;
        predA[base + g * 32 + r] = (f16x8){PA[o+0],PA[o+1],PA[o+2],PA[o+3],PA[o+4],PA[o+5],PA[o+6],PA[o+7]};
        predB[base + g * 32 + r] = (f16x8){PB[o+0],PB[o+1],PB[o+2],PB[o+3],PB[o+4],PB[o+5],PB[o+6],PB[o+7]};
        tgtA[base + g * 32 + r]  = (f16x8){TA[o+0],TA[o+1],TA[o+2],TA[o+3],TA[o+4],TA[o+5],TA[o+6],TA[o+7]};
        tgtB[base + g * 32 + r]  = (f16x8){TB[o+0],TB[o+1],TB[o+2],TB[o+3],TB[o+4],TB[o+5],TB[o+6],TB[o+7]};
    }

    unsigned long long mb = __ballot(valid);
    if ((threadIdx.x & 63) == 0)
        cnt4[idx >> 6] = (unsigned int)__popcll(mb);
}

// Round-10: R7 loop VERBATIM (best: 28.3 us). ONE structural change:
// final_kernel's dispatch node is removed; the LAST mfma block (atomic
// ticket) runs the exact same reduction. R2's version of this cost +25 us
// because each block executed __threadfence() = device-scope fence = L2
// writeback-invalidate on non-coherent XCDs, 1024x. This version has ZERO
// cache-maintenance instructions:
//  - psum written with AGENT-scope RELAXED atomic stores (sc-bit stores
//    that bypass L2 and land at the device-coherent point; no RMW);
//  - s_waitcnt vmcnt(0) guarantees those stores COMPLETED before the
//    ticket atomicAdd (also agent-scope, same coherent point) -> any block
//    observing tk==511 observes completed psum values;
//  - last block reads psum with AGENT-scope RELAXED atomic loads
//    (pipelined loads, not RMW); cnt4 via normal loads (written by prep;
//    L2s are invalidated at the dispatch boundary and no one cached cnt4
//    this dispatch). asm memory clobbers pin compiler ordering.
// Reduction is the byte-exact final_kernel body -> bitwise-identical out.
__global__ __launch_bounds__(256, 2) void chamfer_mfma_kernel(
        const f16x8* __restrict__ predA, const f16x8* __restrict__ predB,
        const f16x8* __restrict__ tgtA, const f16x8* __restrict__ tgtB,
        const float* __restrict__ czero, float* psum,
        const unsigned int* __restrict__ cnt4,
        unsigned int* ticket, float* __restrict__ out) {
    int bid = blockIdx.x;
    int lin = (bid & 7) * 64 + (bid >> 3);    // XCD-contiguous logical id
    int qg8 = lin & 15; lin >>= 4;            // qg8(16) fastest, b(16), dir(2)
    int b   = lin & 15; lin >>= 4;
    int dir = lin;                            // 0: queries=pred, refs=target
    int j0 = dir * 512 + b * 32 + qg8 * 2;    // old logical psum slots
    int j1 = j0 + 1;

    const f16x8* __restrict__ Apack = dir ? predA : tgtA;  // refs
    const f16x8* __restrict__ Bpack = dir ? tgtB  : predB; // queries

    int tid = threadIdx.x;
    int w = tid >> 6, l = tid & 63;

    __shared__ float comb[4][8][64];

    f16x8 bq[8];
    #pragma unroll
    for (int qt = 0; qt < 8; ++qt)
        bq[qt] = Bpack[((size_t)(b * 128 + qg8 * 8 + qt)) * 64 + l];

    // opaque zero C-operand (value IS zero; provenance hidden from compiler)
    f32x16 cz = *(const f32x16*)czero;

    float qA[8], qB[8];
    #pragma unroll
    for (int qt = 0; qt < 8; ++qt) { qA[qt] = QMIN0; qB[qt] = QMIN0; }

    size_t abase = ((size_t)(b * 128)) * 64 + (size_t)w * 64 + l;
    #pragma unroll 4
    for (int t = 0; t < 32; ++t) {
        f16x8 a = Apack[abase + (size_t)t * 256];
        #pragma unroll
        for (int qt = 0; qt < 8; ++qt) {
            f32x16 d = __builtin_amdgcn_mfma_f32_32x32x16_f16(a, bq[qt], cz, 0, 0, 0);
            #pragma unroll
            for (int i = 0; i < 4; ++i) {
                qA[qt] = fminf(fminf(qA[qt], d[4 * i + 0]), d[4 * i + 1]);  // -> v_min3
                qB[qt] = fminf(fminf(qB[qt], d[4 * i + 2]), d[4 * i + 3]);  // -> v_min3
            }
        }
    }

    #pragma unroll
    for (int qt = 0; qt < 8; ++qt) comb[w][qt][l] = fminf(qA[qt], qB[qt]);
    __syncthreads();

    // Two independent reductions, each the EXACT old-block computation.
    float c0 = 0.0f, c1 = 0.0f;
    if (tid < 128) {
        int qt = tid >> 5, c = tid & 31;
        float m0 = QMIN0, m1 = QMIN0;
        #pragma unroll
        for (int ww = 0; ww < 4; ++ww)
            #pragma unroll
            for (int h = 0; h < 2; ++h) {
                m0 = fminf(m0, comb[ww][qt][h * 32 + c]);
                m1 = fminf(m1, comb[ww][qt + 4][h * 32 + c]);
            }
        // m < -1e4 marks an invalid query (w_q = -WBIG); contributes 0
        c0 = (m0 < -1e4f) ? 0.0f : sqrtf(fmaxf(m0, 1e-12f));
        c1 = (m1 < -1e4f) ? 0.0f : sqrtf(fmaxf(m1, 1e-12f));
    }
    for (int off = 32; off; off >>= 1) {
        c0 += __shfl_down(c0, off, 64);
        c1 += __shfl_down(c1, off, 64);
    }
    __shared__ float ps0[4], ps1[4];
    if ((tid & 63) == 0) { ps0[tid >> 6] = c0; ps1[tid >> 6] = c1; }
    __syncthreads();

    // ---- fence-free ticket finish ----
    __shared__ unsigned int lastflag;
    if (tid == 0) {
        float s0 = ps0[0] + ps0[1] + ps0[2] + ps0[3];
        float s1 = ps1[0] + ps1[1] + ps1[2] + ps1[3];
        __hip_atomic_store(&psum[j0], s0, __ATOMIC_RELAXED, __HIP_MEMORY_SCOPE_AGENT);
        __hip_atomic_store(&psum[j1], s1, __ATOMIC_RELAXED, __HIP_MEMORY_SCOPE_AGENT);
        asm volatile("s_waitcnt vmcnt(0)" ::: "memory");  // stores completed
        unsigned int tk = __hip_atomic_fetch_add(ticket, 1u, __ATOMIC_RELAXED,
                                                 __HIP_MEMORY_SCOPE_AGENT);
        lastflag = (tk == (unsigned int)(MGRID - 1)) ? 1u : 0u;
    }
    __syncthreads();
    if (!lastflag) return;
    asm volatile("" ::: "memory");   // no reordering of the reads above this

    // EXACT final_kernel body (same order) on 256 threads.
    unsigned int c = 0;
    float s = 0.0f;
    #pragma unroll
    for (int i = 0; i < 4; ++i) {
        c += cnt4[tid + 256 * i];
        s += __hip_atomic_load(&psum[tid + 256 * i], __ATOMIC_RELAXED,
                               __HIP_MEMORY_SCOPE_AGENT);
    }
    for (int off = 32; off; off >>= 1) {
        c += __shfl_down(c, off, 64);
        s += __shfl_down(s, off, 64);
    }
    __shared__ unsigned int cs[4];
    __shared__ float ss[4];
    if ((tid & 63) == 0) { cs[tid >> 6] = c; ss[tid >> 6] = s; }
    __syncthreads();
    if (tid == 0) {
        unsigned int C = cs[0] + cs[1] + cs[2] + cs[3];
        float S = ss[0] + ss[1] + ss[2] + ss[3];
        out[0] = S * 0.5f / ((float)C + 1e-8f);
    }
}

extern "C" void kernel_launch(void* const* d_in, const int* in_sizes, int n_in,
                              void* d_out, int out_size, void* d_ws, size_t ws_size,
                              hipStream_t stream) {
    const float* pred = (const float*)d_in[0];
    const float* target = (const float*)d_in[1];
    const int* mask = (const int*)d_in[2];
    float* out = (float*)d_out;

    // ws: [predA 2M | predB 2M | tgtA 2M | tgtB 2M | psum 4K | cnt4 4K | czero 64B | ticket 4B]
    char* ws = (char*)d_ws;
    size_t off = 0;
    f16x8* predA = (f16x8*)(ws + off); off += FRAG_BYTES;
    f16x8* predB = (f16x8*)(ws + off); off += FRAG_BYTES;
    f16x8* tgtA  = (f16x8*)(ws + off); off += FRAG_BYTES;
    f16x8* tgtB  = (f16x8*)(ws + off); off += FRAG_BYTES;
    float* psum = (float*)(ws + off); off += NPSUM * sizeof(float);
    unsigned int* cnt4 = (unsigned int*)(ws + off); off += 1024 * sizeof(unsigned int);
    float* czero = (float*)(ws + off); off += 64;
    unsigned int* ticket = (unsigned int*)(ws + off); off += sizeof(unsigned int);

    prep_kernel<<<NPTS / 256, 256, 0, stream>>>(
        pred, target, mask, predA, predB, tgtA, tgtB, cnt4, czero, ticket);
    chamfer_mfma_kernel<<<MGRID, 256, 0, stream>>>(
        predA, predB, tgtA, tgtB, czero, psum, cnt4, ticket, out);
}

// Round 11
// 28.036 us; speedup vs baseline: 1.1533x; 1.1533x over previous
//
#include <hip/hip_runtime.h>
#include <math.h>

typedef _Float16 f16;
typedef f16 f16x8 __attribute__((ext_vector_type(8)));
typedef float f32x16 __attribute__((ext_vector_type(16)));

static constexpr int Bn = 16;
static constexpr int Kn = 4096;
static constexpr int NPTS = Bn * Kn;    // 65536
static constexpr int MGRID = 512;       // qg8(16) x b(16) x dir(2)
static constexpr int NPSUM = 1024;      // psum keeps the OLD 1024-slot layout
static constexpr float WBIG = 49152.0f; // exact in fp16
static constexpr float QMIN0 = 3e37f;

// Round-11: prep_kernel is GONE. R2's arithmetic (prep+mfma+tail=52.1,
// mfma dispatch=43.5) showed prep + one boundary ~= 8.6 us for ~10 MB of
// traffic — mostly dispatch overhead + the 8.4 MB fragment round-trip.
// The mfma kernel itself has been insensitive to traffic/TLP/ILP for five
// rounds (R5-R9: <=1 us movement), so the remaining fat is pipeline
// structure. Each lane now builds its MFMA fragments IN-REGISTER from the
// raw pred/target/mask (12B+4B per point instead of 64B of precomputed
// fragments): ~30 VALU ops/t, hidden under the ~256-cyc/t MFMA shadow
// (VALUBusy was only ~17%). Same mk_slots ops on same inputs -> bit-
// identical f16 fragments -> bit-identical MFMA stream -> bitwise output.
//  - cnt4: dir=0 blocks ballot their own 8 query-tile masks (same
//    per-64-point popcounts as old prep; uint sums exact).
//  - czero: replaced by opaque zero via inline asm (v_mov_b32 0) — value
//    provably 0 at runtime, provenance hidden from the constant folder.
//  - Ticket tails are dead (R2 +25us fenced, R10 +4us fence-free):
//    final_kernel stays a separate dispatch, byte-identical.
// Register budget: bq 64 + cz 16 + qA/qB 16 + slot temps ~20 + addr ~12
// ~= 130-160 VGPR << 256 cap at (256,2) with grid 512 = exactly 2
// blocks/CU -> no clamp-spill (R4/R6 signature: VGPR pinned + WRITE_SIZE
// balloon; tripwire to check).
__global__ __launch_bounds__(256, 2) void chamfer_fused_kernel(
        const float* __restrict__ pred, const float* __restrict__ target,
        const int* __restrict__ mask,
        float* __restrict__ psum, unsigned int* __restrict__ cnt4) {
    int bid = blockIdx.x;
    int lin = (bid & 7) * 64 + (bid >> 3);    // XCD-contiguous logical id
    int qg8 = lin & 15; lin >>= 4;            // qg8(16) fastest, b(16), dir(2)
    int b   = lin & 15; lin >>= 4;
    int dir = lin;                            // 0: queries=pred, refs=target
    int j0 = dir * 512 + b * 32 + qg8 * 2;    // old logical psum slots
    int j1 = j0 + 1;

    const float* __restrict__ Araw = dir ? pred : target;  // refs
    const float* __restrict__ Braw = dir ? target : pred;  // queries

    int tid = threadIdx.x;
    int w = tid >> 6, l = tid & 63;
    int r = l & 31, g = l >> 5;

    __shared__ float comb[4][8][64];

    // opaque zero C-operand: runtime value IS 0, provenance hidden.
    float zf;
    asm volatile("v_mov_b32 %0, 0" : "=v"(zf));
    f32x16 cz;
    #pragma unroll
    for (int i = 0; i < 16; ++i) cz[i] = zf;

    const f16 one = (f16)1.0f, zero = (f16)0.0f;

    // ---- B fragments for this block's 8 query tiles (same bit-values as
    // old prep's B slots: B = {xh,xl,xh,yh,yl,yh,zh,zl | zh,1,1,whB,wlB,0,0,0})
    f16x8 bq[8];
    unsigned int bcnt[8];
    #pragma unroll
    for (int qt = 0; qt < 8; ++qt) {
        int idx = b * 4096 + (qg8 * 8 + qt) * 32 + r;
        bool valid = mask[idx] != 0;
        float x = Braw[idx * 3 + 0], y = Braw[idx * 3 + 1], z = Braw[idx * 3 + 2];
        if (!valid) { x = 0.0f; y = 0.0f; z = 0.0f; }
        float wv = fmaf(x, x, fmaf(y, y, z * z));
        f16 xh = (f16)x, yh = (f16)y, zh = (f16)z;
        f16 xl = (f16)(x - (float)xh), yl = (f16)(y - (float)yh), zl = (f16)(z - (float)zh);
        f16 whB, wlB;
        if (valid) { f16 wh = (f16)wv; whB = wh; wlB = (f16)(wv - (float)wh); }
        else       { whB = (f16)(-WBIG); wlB = zero; }
        f16x8 blo = {xh, xl, xh, yh, yl, yh, zh, zl};
        f16x8 bhi = {zh, one, one, whB, wlB, zero, zero, zero};
        bq[qt] = g ? bhi : blo;
        // lanes r and r+32 hold the same point -> popcll is 2x the count
        unsigned long long mb = __ballot(valid);
        bcnt[qt] = (unsigned int)__popcll(mb) >> 1;
    }
    // dir=0 blocks own cnt4 slots b*64 + qg8*4 + m (64 consecutive points
    // each = qt pair (2m,2m+1)) — same values as old prep's ballots.
    if (dir == 0 && w == 0 && l == 0) {
        #pragma unroll
        for (int m = 0; m < 4; ++m)
            cnt4[b * 64 + qg8 * 4 + m] = bcnt[2 * m] + bcnt[2 * m + 1];
    }

    float qA[8], qB[8];
    #pragma unroll
    for (int qt = 0; qt < 8; ++qt) { qA[qt] = QMIN0; qB[qt] = QMIN0; }

    // wave w covers ref tiles rt = w + 4t, t = 0..31 (R7's exact order).
    #pragma unroll 4
    for (int t = 0; t < 32; ++t) {
        int idxA = b * 4096 + (w + 4 * t) * 32 + r;
        bool valid = mask[idxA] != 0;
        float x = Araw[idxA * 3 + 0], y = Araw[idxA * 3 + 1], z = Araw[idxA * 3 + 2];
        if (!valid) { x = 0.0f; y = 0.0f; z = 0.0f; }
        // A slots (bit-identical to old prep):
        // A = {m2xh,m2xh,m2xl,m2yh,m2yh,m2yl,m2zh,m2zh | m2zl,whA,wlA,1,1,0,0,0}
        float wv = fmaf(x, x, fmaf(y, y, z * z));
        f16 xh = (f16)x, yh = (f16)y, zh = (f16)z;
        f16 xl = (f16)(x - (float)xh), yl = (f16)(y - (float)yh), zl = (f16)(z - (float)zh);
        f16 m2xh = (f16)(-2.0f * (float)xh), m2xl = (f16)(-2.0f * (float)xl);
        f16 m2yh = (f16)(-2.0f * (float)yh), m2yl = (f16)(-2.0f * (float)yl);
        f16 m2zh = (f16)(-2.0f * (float)zh), m2zl = (f16)(-2.0f * (float)zl);
        f16 whA, wlA;
        if (valid) { f16 wh = (f16)wv; whA = wh; wlA = (f16)(wv - (float)wh); }
        else       { whA = (f16)WBIG; wlA = zero; }
        f16x8 alo = {m2xh, m2xh, m2xl, m2yh, m2yh, m2yl, m2zh, m2zh};
        f16x8 ahi = {m2zl, whA, wlA, one, one, zero, zero, zero};
        f16x8 a = g ? ahi : alo;

        #pragma unroll
        for (int qt = 0; qt < 8; ++qt) {
            f32x16 d = __builtin_amdgcn_mfma_f32_32x32x16_f16(a, bq[qt], cz, 0, 0, 0);
            #pragma unroll
            for (int i = 0; i < 4; ++i) {
                qA[qt] = fminf(fminf(qA[qt], d[4 * i + 0]), d[4 * i + 1]);  // -> v_min3
                qB[qt] = fminf(fminf(qB[qt], d[4 * i + 2]), d[4 * i + 3]);  // -> v_min3
            }
        }
    }

    #pragma unroll
    for (int qt = 0; qt < 8; ++qt) comb[w][qt][l] = fminf(qA[qt], qB[qt]);
    __syncthreads();

    // Two independent reductions, each the EXACT old-block computation.
    float c0 = 0.0f, c1 = 0.0f;
    if (tid < 128) {
        int qt = tid >> 5, c = tid & 31;
        float m0 = QMIN0, m1 = QMIN0;
        #pragma unroll
        for (int ww = 0; ww < 4; ++ww)
            #pragma unroll
            for (int h = 0; h < 2; ++h) {
                m0 = fminf(m0, comb[ww][qt][h * 32 + c]);
                m1 = fminf(m1, comb[ww][qt + 4][h * 32 + c]);
            }
        // m < -1e4 marks an invalid query (w_q = -WBIG); contributes 0
        c0 = (m0 < -1e4f) ? 0.0f : sqrtf(fmaxf(m0, 1e-12f));
        c1 = (m1 < -1e4f) ? 0.0f : sqrtf(fmaxf(m1, 1e-12f));
    }
    for (int off = 32; off; off >>= 1) {
        c0 += __shfl_down(c0, off, 64);
        c1 += __shfl_down(c1, off, 64);
    }
    __shared__ float ps0[4], ps1[4];
    if ((tid & 63) == 0) { ps0[tid >> 6] = c0; ps1[tid >> 6] = c1; }
    __syncthreads();
    if (tid == 0) {
        psum[j0] = ps0[0] + ps0[1] + ps0[2] + ps0[3];
        psum[j1] = ps1[0] + ps1[1] + ps1[2] + ps1[3];
    }
}

__global__ __launch_bounds__(256) void final_kernel(
        const unsigned int* __restrict__ cnt4, const float* __restrict__ psum,
        float* __restrict__ out) {
    int t = threadIdx.x;
    unsigned int c = 0;
    float s = 0.0f;
    #pragma unroll
    for (int i = 0; i < 4; ++i) {
        c += cnt4[t + 256 * i];
        s += psum[t + 256 * i];
    }
    for (int off = 32; off; off >>= 1) {
        c += __shfl_down(c, off, 64);
        s += __shfl_down(s, off, 64);
    }
    __shared__ unsigned int cs[4];
    __shared__ float ss[4];
    if ((t & 63) == 0) { cs[t >> 6] = c; ss[t >> 6] = s; }
    __syncthreads();
    if (t == 0) {
        unsigned int C = cs[0] + cs[1] + cs[2] + cs[3];
        float S = ss[0] + ss[1] + ss[2] + ss[3];
        out[0] = S * 0.5f / ((float)C + 1e-8f);
    }
}

extern "C" void kernel_launch(void* const* d_in, const int* in_sizes, int n_in,
                              void* d_out, int out_size, void* d_ws, size_t ws_size,
                              hipStream_t stream) {
    const float* pred = (const float*)d_in[0];
    const float* target = (const float*)d_in[1];
    const int* mask = (const int*)d_in[2];
    float* out = (float*)d_out;

    // ws: [psum 4K | cnt4 4K]
    char* ws = (char*)d_ws;
    float* psum = (float*)ws;
    unsigned int* cnt4 = (unsigned int*)(ws + NPSUM * sizeof(float));

    chamfer_fused_kernel<<<MGRID, 256, 0, stream>>>(
        pred, target, mask, psum, cnt4);
    final_kernel<<<1, 256, 0, stream>>>(cnt4, psum, out);
}